// Round 1
// baseline (166.796 us; speedup 1.0000x reference)
//
#include <hip/hip_runtime.h>

#define B_ 2
#define N_ 6
#define D_ 41
#define H_ 16
#define W_ 44
#define C_ 64
#define X_ 200
#define Y_ 200
#define NPTS (B_*N_*D_*H_*W_)   // 346368
#define NBN (B_*N_)             // 12
#define MAT_STRIDE 24           // doubles per (b,n)

__device__ inline void inv3x3(const double m[9], double out[9]) {
    double a=m[0],b=m[1],c=m[2],d=m[3],e=m[4],f=m[5],g=m[6],h=m[7],i=m[8];
    double A  =  (e*i - f*h);
    double Bm = -(d*i - f*g);
    double Cm =  (d*h - e*g);
    double det = a*A + b*Bm + c*Cm;
    double id = 1.0/det;
    out[0] = A*id;   out[1] = -(b*i - c*h)*id; out[2] =  (b*f - c*e)*id;
    out[3] = Bm*id;  out[4] =  (a*i - c*g)*id; out[5] = -(a*f - c*d)*id;
    out[6] = Cm*id;  out[7] = -(a*h - b*g)*id; out[8] =  (a*e - b*d)*id;
}

// One thread per (b,n): compute inv(post_rots), comb = rot(inv(extr)) @ inv(K), trans.
__global__ void prep_kernel(const float* __restrict__ post_rots,
                            const float* __restrict__ intr,
                            const float* __restrict__ extr,
                            double* __restrict__ mats) {
    int bn = threadIdx.x;
    if (bn >= NBN) return;

    double pr[9], prinv[9], kk[9], kin[9];
    for (int i=0;i<9;i++) pr[i] = (double)post_rots[bn*9+i];
    inv3x3(pr, prinv);
    for (int i=0;i<9;i++) kk[i] = (double)intr[bn*9+i];
    inv3x3(kk, kin);

    // 4x4 inverse, Gauss-Jordan with partial pivoting (f64)
    double a[4][8];
    for (int i=0;i<4;i++)
        for (int j=0;j<4;j++){ a[i][j] = (double)extr[bn*16+i*4+j]; a[i][4+j] = (i==j)?1.0:0.0; }
    for (int col=0; col<4; col++){
        int piv = col; double best = fabs(a[col][col]);
        for (int r=col+1;r<4;r++){ double v=fabs(a[r][col]); if (v>best){best=v;piv=r;} }
        if (piv != col) for (int j=0;j<8;j++){ double t=a[col][j]; a[col][j]=a[piv][j]; a[piv][j]=t; }
        double ip = 1.0/a[col][col];
        for (int j=0;j<8;j++) a[col][j] *= ip;
        for (int r=0;r<4;r++){
            if (r==col) continue;
            double f = a[r][col];
            for (int j=0;j<8;j++) a[r][j] -= f*a[col][j];
        }
    }
    double rot[9], trans[3];
    for (int i=0;i<3;i++){ for (int j=0;j<3;j++) rot[i*3+j]=a[i][4+j]; trans[i]=a[i][4+3]; }
    double comb[9];
    for (int i=0;i<3;i++) for (int j=0;j<3;j++)
        comb[i*3+j] = rot[i*3+0]*kin[0+j] + rot[i*3+1]*kin[3+j] + rot[i*3+2]*kin[6+j];

    double* o = mats + (size_t)bn*MAT_STRIDE;
    for (int i=0;i<9;i++) o[i]   = prinv[i];
    for (int i=0;i<9;i++) o[9+i] = comb[i];
    for (int i=0;i<3;i++) o[18+i]= trans[i];
}

// One wave (64 lanes) per frustum point; lane = channel.
// STAGED=1: dst layout (B, X, Y, C)  -> channel-contiguous atomics
// STAGED=0: dst layout (B, C, X, Y)  -> direct into output
template<int STAGED>
__global__ __launch_bounds__(256)
void scatter_kernel(const float* __restrict__ feat,
                    const float* __restrict__ post_trans,
                    const float* __restrict__ frustum,
                    const float* __restrict__ bev_res,
                    const float* __restrict__ bev_start,
                    const double* __restrict__ mats,
                    float* __restrict__ dst) {
    int tid  = blockIdx.x * blockDim.x + threadIdx.x;
    int wave = tid >> 6;
    int lane = tid & 63;
    if (wave >= NPTS) return;

    int w = wave % W_; int t = wave / W_;
    int h = t % H_;  t /= H_;
    int d = t % D_;  t /= D_;
    int n = t % N_;  int b = t / N_;
    int bn = b*N_ + n;

    const double* M = mats + (size_t)bn*MAT_STRIDE;
    int fidx = ((d*H_ + h)*W_ + w)*3;
    double fx = (double)frustum[fidx+0];
    double fy = (double)frustum[fidx+1];
    double fz = (double)frustum[fidx+2];

    double px = fx - (double)post_trans[bn*3+0];
    double py = fy - (double)post_trans[bn*3+1];
    double pz = fz - (double)post_trans[bn*3+2];

    double q0 = M[0]*px + M[1]*py + M[2]*pz;
    double q1 = M[3]*px + M[4]*py + M[5]*pz;
    double q2 = M[6]*px + M[7]*py + M[8]*pz;

    double r0 = q0*q2, r1 = q1*q2, r2 = q2;

    double gx = M[9]*r0  + M[10]*r1 + M[11]*r2 + M[18];
    double gy = M[12]*r0 + M[13]*r1 + M[14]*r2 + M[19];
    double gz = M[15]*r0 + M[16]*r1 + M[17]*r2 + M[20];

    double resx = (double)bev_res[0], resy = (double)bev_res[1], resz = (double)bev_res[2];
    double sx = (double)bev_start[0] - resx*0.5;
    double sy = (double)bev_start[1] - resy*0.5;
    double sz = (double)bev_start[2] - resz*0.5;

    int cx = (int)((gx - sx)/resx);
    int cy = (int)((gy - sy)/resy);
    int cz = (int)((gz - sz)/resz);

    if (cx < 0 || cx >= X_ || cy < 0 || cy >= Y_ || cz != 0) return;

    float v = feat[(size_t)wave*C_ + lane];
    if (STAGED) {
        atomicAdd(&dst[((size_t)(b*X_ + cx)*Y_ + cy)*C_ + lane], v);
    } else {
        atomicAdd(&dst[((size_t)(b*C_ + lane)*X_ + cx)*Y_ + cy], v);
    }
}

// (B, X*Y, C) -> (B, C, X*Y) tiled transpose
__global__ __launch_bounds__(512)
void transpose_kernel(const float* __restrict__ ws, float* __restrict__ out) {
    __shared__ float tile[64][65];
    int b   = blockIdx.y;
    int xy0 = blockIdx.x * 64;
    int tx  = threadIdx.x;   // 0..63
    int ty  = threadIdx.y;   // 0..7

    #pragma unroll
    for (int i=0;i<8;i++){
        int xy = xy0 + ty + i*8;
        tile[ty + i*8][tx] = ws[((size_t)b*(X_*Y_) + xy)*C_ + tx];
    }
    __syncthreads();
    #pragma unroll
    for (int i=0;i<8;i++){
        int c = ty + i*8;
        out[((size_t)(b*C_ + c))*(X_*Y_) + xy0 + tx] = tile[tx][c];
    }
}

extern "C" void kernel_launch(void* const* d_in, const int* in_sizes, int n_in,
                              void* d_out, int out_size, void* d_ws, size_t ws_size,
                              hipStream_t stream) {
    const float* feat       = (const float*)d_in[0];
    const float* post_trans = (const float*)d_in[1];
    const float* post_rots  = (const float*)d_in[2];
    const float* intr       = (const float*)d_in[3];
    const float* extr       = (const float*)d_in[4];
    const float* frustum    = (const float*)d_in[5];
    const float* bev_res    = (const float*)d_in[6];
    const float* bev_start  = (const float*)d_in[7];
    float* out = (float*)d_out;

    double* mats = (double*)d_ws;
    const size_t mat_bytes  = 4096;
    const size_t feat_bytes = (size_t)B_*X_*Y_*C_*sizeof(float); // 20,480,000
    bool staged = (ws_size >= mat_bytes + feat_bytes);

    hipLaunchKernelGGL(prep_kernel, dim3(1), dim3(16), 0, stream,
                       post_rots, intr, extr, mats);

    const int total_threads = NPTS * 64;
    const int blocks = (total_threads + 255) / 256;

    if (staged) {
        float* ws_feat = (float*)((char*)d_ws + mat_bytes);
        hipMemsetAsync(ws_feat, 0, feat_bytes, stream);
        scatter_kernel<1><<<blocks, 256, 0, stream>>>(feat, post_trans, frustum,
                                                      bev_res, bev_start, mats, ws_feat);
        transpose_kernel<<<dim3((X_*Y_)/64, B_), dim3(64,8), 0, stream>>>(ws_feat, out);
    } else {
        hipMemsetAsync(out, 0, (size_t)out_size * sizeof(float), stream);
        scatter_kernel<0><<<blocks, 256, 0, stream>>>(feat, post_trans, frustum,
                                                      bev_res, bev_start, mats, out);
    }
}